// Round 7
// baseline (440.573 us; speedup 1.0000x reference)
//
#include <hip/hip_runtime.h>
#include <math.h>

#define NQ 12
#define DIM 4096
#define NGATES 36
#define NPAIR 5

typedef float f32x2 __attribute__((ext_vector_type(2)));

// GF(2)-linear LDS swizzle (bijective on 12 bits): sw(a^b) = sw(a)^sw(b)
constexpr unsigned swz(unsigned x) { return x ^ (x >> 4); }

// ---- compile-time circuit plan ----
// CNOTs folded into GF(2) index maps (M, M^-1). Gates grouped 4/round,
// rounds paired: pair p covers gates 8p..8p+7 (rounds 2p, 2p+1). The 8 masks
// + 2 free dims span a 10-dim subspace V; each wave owns one 1024-amp coset
// of V for BOTH rounds -> mid-pair exchange is wave-local (no __syncthreads).
struct PairT {
  unsigned lbA[6], lbB[6];   // lane bases (6 bits -> 64 lanes) per sub-round
  unsigned wb[2];            // wave basis (2 bits -> 4 waves)
  unsigned cbA8[16], cbB8[16]; // swizzled byte offsets of 16 coset slots
  unsigned sA[4], sB[4];     // selectors ("1-branch" parity masks)
};
struct PlanT {
  PairT pr[NPAIR];
  unsigned zsel[NQ];
  bool ok;
};

constexpr int rnk12(const unsigned* v) {
  unsigned r[12] = {};
  for (int i = 0; i < 12; ++i) r[i] = v[i];
  int rk = 0;
  for (int a = 0; a < 12; ++a) {
    if (!r[a]) continue;
    unsigned piv = r[a] & (0u - r[a]);
    ++rk;
    for (int b = a + 1; b < 12; ++b) if (r[b] & piv) r[b] ^= r[a];
  }
  return rk;
}

constexpr PlanT make_plan() {
  PlanT P{};
  P.ok = true;
  unsigned Mcol[NQ] = {}, Minv[NQ] = {};
  for (int i = 0; i < NQ; ++i) { Mcol[i] = 1u << i; Minv[i] = 1u << i; }
  unsigned gm[NGATES] = {}, gs[NGATES] = {};
  int g = 0;
  for (int L = 0; L < 3; ++L) {
    for (int q = 0; q < NQ; ++q) { int b = NQ - 1 - q; gm[g] = Mcol[b]; gs[g] = Minv[b]; ++g; }
    for (int q = 0; q < NQ; ++q) {
      int bc = NQ - 1 - q, bt = NQ - 1 - ((q + 1) % NQ);
      Mcol[bc] ^= Mcol[bt];
      Minv[bt] ^= Minv[bc];
    }
  }
  for (int p = 0; p < NPAIR; ++p) {
    const int gb = 8 * p;
    const bool hasB = (p < 4);
    unsigned mA[4] = {}, mB[4] = {};
    for (int k = 0; k < 4; ++k) { mA[k] = gm[gb + k]; P.pr[p].sA[k] = gs[gb + k]; }
    if (hasB)
      for (int k = 0; k < 4; ++k) { mB[k] = gm[gb + 4 + k]; P.pr[p].sB[k] = gs[gb + 4 + k]; }
    // forward elimination over the pair's masks -> pivot set
    unsigned rows[8] = {mA[0], mA[1], mA[2], mA[3], mB[0], mB[1], mB[2], mB[3]};
    const int nr = hasB ? 8 : 4;
    unsigned pivmask = 0;
    for (int a = 0; a < nr; ++a) {
      unsigned piv = rows[a] & (0u - rows[a]);
      pivmask |= piv;
      for (int b = a + 1; b < nr; ++b) if (rows[b] & piv) rows[b] ^= rows[a];
    }
    unsigned fr[12] = {}; int nf = 0;
    for (int bit = 0; bit < 12; ++bit)
      if (!((pivmask >> bit) & 1u)) fr[nf++] = 1u << bit;
    if (hasB) {
      if (nf != 4) P.ok = false;
      for (int k = 0; k < 4; ++k) { P.pr[p].lbA[k] = mB[k]; P.pr[p].lbB[k] = mA[k]; }
      P.pr[p].lbA[4] = fr[0]; P.pr[p].lbA[5] = fr[1];
      P.pr[p].lbB[4] = fr[0]; P.pr[p].lbB[5] = fr[1];
      P.pr[p].wb[0] = fr[2];  P.pr[p].wb[1] = fr[3];
    } else {
      if (nf != 8) P.ok = false;
      for (int k = 0; k < 6; ++k) { P.pr[p].lbA[k] = fr[k]; P.pr[p].lbB[k] = fr[k]; }
      P.pr[p].wb[0] = fr[6]; P.pr[p].wb[1] = fr[7];
    }
    for (int d = 0; d < 16; ++d) {
      unsigned cA = 0, cB = 0;
      for (int k = 0; k < 4; ++k) if (d & (1 << k)) { cA ^= mA[k]; cB ^= mB[k]; }
      P.pr[p].cbA8[d] = swz(cA) << 3;
      P.pr[p].cbB8[d] = swz(cB) << 3;
    }
    // validity: sub-round bases must span all 12 dims (bijection onto state)
    unsigned vA[12] = {mA[0], mA[1], mA[2], mA[3],
                       P.pr[p].lbA[0], P.pr[p].lbA[1], P.pr[p].lbA[2],
                       P.pr[p].lbA[3], P.pr[p].lbA[4], P.pr[p].lbA[5],
                       P.pr[p].wb[0], P.pr[p].wb[1]};
    if (rnk12(vA) != 12) P.ok = false;
    if (hasB) {
      unsigned vB[12] = {mB[0], mB[1], mB[2], mB[3],
                         P.pr[p].lbB[0], P.pr[p].lbB[1], P.pr[p].lbB[2],
                         P.pr[p].lbB[3], P.pr[p].lbB[4], P.pr[p].lbB[5],
                         P.pr[p].wb[0], P.pr[p].wb[1]};
      if (rnk12(vB) != 12) P.ok = false;
    }
    // delta property: parity(m_i & s_k) == (i==k) within each sub-round
    for (int i = 0; i < 4; ++i)
      for (int k = 0; k < 4; ++k) {
        if ((__builtin_popcount(mA[i] & P.pr[p].sA[k]) & 1) != (i == k ? 1 : 0)) P.ok = false;
        if (hasB && (__builtin_popcount(mB[i] & P.pr[p].sB[k]) & 1) != (i == k ? 1 : 0)) P.ok = false;
      }
  }
  for (int q = 0; q < NQ; ++q) P.zsel[q] = Minv[NQ - 1 - q];
  return P;
}

constexpr PlanT PLAN = make_plan();
static_assert(PLAN.ok, "circuit plan failed rank/delta validation");

__device__ __forceinline__ f32x2 blo(f32x2 a) { return __builtin_shufflevector(a, a, 0, 0); }
__device__ __forceinline__ f32x2 bhi(f32x2 a) { return __builtin_shufflevector(a, a, 1, 1); }
__device__ __forceinline__ float rdlane(float v, int lane) {
  return __builtin_bit_cast(float, __builtin_amdgcn_readlane(__builtin_bit_cast(int, v), lane));
}

__global__ __launch_bounds__(256)
__attribute__((amdgpu_waves_per_eu(5, 5)))
void qc_main(const float* __restrict__ x, const float* __restrict__ params,
             float* __restrict__ out) {
  __shared__ float2 sst[DIM];        // exactly 32768 B -> 5 blocks/CU
  char* sb = (char*)sst;
  float* sf = (float*)sst;           // reduction scratch overlaid post-barrier
  const int t = threadIdx.x;
  const long row = blockIdx.x;

  // ---- per-wave gate matrices: lane g computes fused U = RZ*RY*RX of gate g.
  // Coeffs broadcast later via v_readlane (VALU pipe, nothing on DS/SMEM).
  float cf[8];
  {
    const int l = t & 63;
    const int g0 = l < NGATES ? l : 0;
    float h1 = params[3*g0+0]*0.5f, h2 = params[3*g0+1]*0.5f, h3 = params[3*g0+2]*0.5f;
    float c1, s1, c2, s2, c3, s3;
    sincosf(h1, &s1, &c1);
    sincosf(h2, &s2, &c2);
    sincosf(h3, &s3, &c3);
    float a00r =  c2*c1, a00i =  s2*s1;
    float a01r = -s2*c1, a01i = -c2*s1;
    float a10r =  s2*c1, a10i = -c2*s1;
    float a11r =  c2*c1, a11i = -s2*s1;
    cf[0] = c3*a00r + s3*a00i;  cf[1] = c3*a00i - s3*a00r;
    cf[2] = c3*a01r + s3*a01i;  cf[3] = c3*a01i - s3*a01r;
    cf[4] = c3*a10r - s3*a10i;  cf[5] = c3*a10i + s3*a10r;
    cf[6] = c3*a11r - s3*a11i;  cf[7] = c3*a11i + s3*a11r;
  }

  // ---- stage x row (im=0), accumulate sum of squares ----
  const float4* x4 = (const float4*)(x + (size_t)row * DIM);
  float ssq = 0.f;
#pragma unroll
  for (int k = 0; k < 4; ++k) {
    float4 a = x4[t + 256*k];
    int j0 = 4*(t + 256*k);
    *(float2*)(sb + (swz((unsigned)j0)     << 3)) = make_float2(a.x, 0.f);
    *(float2*)(sb + (swz((unsigned)(j0+1)) << 3)) = make_float2(a.y, 0.f);
    *(float2*)(sb + (swz((unsigned)(j0+2)) << 3)) = make_float2(a.z, 0.f);
    *(float2*)(sb + (swz((unsigned)(j0+3)) << 3)) = make_float2(a.w, 0.f);
    ssq += a.x*a.x + a.y*a.y + a.z*a.z + a.w*a.w;
  }
#pragma unroll
  for (int off = 32; off > 0; off >>= 1) ssq += __shfl_down(ssq, off, 64);
  __syncthreads();

  // ---- one sub-round: read 16-amp coset, apply 4 gates, write back ----
  auto subround = [&](const unsigned* lb, const unsigned* cb8, const unsigned* sel,
                      int gbase, unsigned wbase) {
    const unsigned l = (unsigned)t & 63u;
    unsigned jp = wbase;
#pragma unroll
    for (int k = 0; k < 6; ++k)
      jp ^= (unsigned)(-(int)((l >> k) & 1u)) & lb[k];
    // relabel so slot d carries gate-bit pattern d exactly
    unsigned adj8 = 0;
    adj8 ^= (unsigned)(-(int)(__popc(jp & sel[0]) & 1)) & cb8[1];
    adj8 ^= (unsigned)(-(int)(__popc(jp & sel[1]) & 1)) & cb8[2];
    adj8 ^= (unsigned)(-(int)(__popc(jp & sel[2]) & 1)) & cb8[4];
    adj8 ^= (unsigned)(-(int)(__popc(jp & sel[3]) & 1)) & cb8[8];
    const unsigned base8 = ((jp ^ (jp >> 4)) << 3) ^ adj8;

    f32x2 v[16];
#pragma unroll
    for (int d = 0; d < 16; ++d)
      v[d] = *(const f32x2*)(sb + (base8 ^ cb8[d]));
#pragma unroll
    for (int st = 0; st < 4; ++st) {
      const int gg = gbase + st;
      float u0 = rdlane(cf[0], gg), u1 = rdlane(cf[1], gg);
      float u2 = rdlane(cf[2], gg), u3 = rdlane(cf[3], gg);
      float u4 = rdlane(cf[4], gg), u5 = rdlane(cf[5], gg);
      float u6 = rdlane(cf[6], gg), u7 = rdlane(cf[7], gg);
      const f32x2 c0 = {u0, u1}, c1 = {-u1, u0}, c2 = {u2, u3}, c3 = {-u3, u2};
      const f32x2 c4 = {u4, u5}, c5 = {-u5, u4}, c6 = {u6, u7}, c7 = {-u7, u6};
#pragma unroll
      for (int d = 0; d < 16; ++d) {
        if (!(d & (1 << st))) {
          const int d1 = d | (1 << st);
          const f32x2 a0 = v[d], a1 = v[d1];
          f32x2 o0 = c0 * blo(a0);
          o0 += c1 * bhi(a0);
          o0 += c2 * blo(a1);
          o0 += c3 * bhi(a1);
          f32x2 o1 = c4 * blo(a0);
          o1 += c5 * bhi(a0);
          o1 += c6 * blo(a1);
          o1 += c7 * bhi(a1);
          v[d] = o0; v[d1] = o1;
        }
      }
    }
#pragma unroll
    for (int d = 0; d < 16; ++d)
      *(f32x2*)(sb + (base8 ^ cb8[d])) = v[d];
  };

  // ---- 5 pairs; mid-pair exchange is wave-local (no barrier) ----
#pragma unroll 1
  for (int p = 0; p < NPAIR; ++p) {
    const unsigned wbase = ((t & 64) ? PLAN.pr[p].wb[0] : 0u)
                         ^ ((t & 128) ? PLAN.pr[p].wb[1] : 0u);
    subround(PLAN.pr[p].lbA, PLAN.pr[p].cbA8, PLAN.pr[p].sA, 8 * p, wbase);
    if (p < 4)  // wave-local: reads hit only this wave's 1024-amp V-coset
      subround(PLAN.pr[p].lbB, PLAN.pr[p].cbB8, PLAN.pr[p].sB, 8 * p + 4, wbase);
    __syncthreads();
  }

  // ---- measurement: 16 consecutive amps/thread, WHT over low 4 bits ----
  const unsigned mbase8 = (((16u * (unsigned)t) ^ (unsigned)t) << 3);
  float p[16];
#pragma unroll
  for (int c = 0; c < 16; ++c) {
    f32x2 v = *(const f32x2*)(sb + (mbase8 ^ ((unsigned)c << 3)));
    f32x2 sq = v * v;
    p[c] = sq[0] + sq[1];
  }
#pragma unroll
  for (int b = 0; b < 4; ++b) {
#pragma unroll
    for (int c = 0; c < 16; ++c) {
      if (!(c & (1 << b))) {
        const int c1 = c | (1 << b);
        float u = p[c], v = p[c1];
        p[c] = u + v; p[c1] = u - v;
      }
    }
  }
  float zs[NQ];
#pragma unroll
  for (int q = 0; q < NQ; ++q) {
    const unsigned m = PLAN.zsel[q];
    const float v = p[m & 15u];
    const int sgn = __popc((unsigned)t & (m >> 4)) & 1;
    zs[q] = sgn ? -v : v;
  }
#pragma unroll
  for (int q = 0; q < NQ; ++q) {
#pragma unroll
    for (int off = 32; off > 0; off >>= 1) zs[q] += __shfl_down(zs[q], off, 64);
  }
  __syncthreads();               // all state reads done; safe to overlay sf
  const int w = t >> 6;
  if ((t & 63) == 0) {
#pragma unroll
    for (int q = 0; q < NQ; ++q) sf[w*NQ + q] = zs[q];
    sf[48 + w] = ssq;
  }
  __syncthreads();
  if (t < NQ) {
    const float den = sf[48] + sf[49] + sf[50] + sf[51];
    const float tot = sf[t] + sf[NQ + t] + sf[2*NQ + t] + sf[3*NQ + t];
    out[row * NQ + t] = tot / den;
  }
}

extern "C" void kernel_launch(void* const* d_in, const int* in_sizes, int n_in,
                              void* d_out, int out_size, void* d_ws, size_t ws_size,
                              hipStream_t stream) {
  const float* x = (const float*)d_in[0];
  const float* params = (const float*)d_in[1];
  float* out = (float*)d_out;
  const int nrows = in_sizes[0] / DIM;         // 8192
  qc_main<<<dim3(nrows), dim3(256), 0, stream>>>(x, params, out);
}